// Round 2
// baseline (353.879 us; speedup 1.0000x reference)
//
#include <hip/hip_runtime.h>
#include <hip/hip_bf16.h>
#include <stdint.h>

// CIGTLayer: fp8 block-quant roundtrips + gating + 4-path batched GEMM.
// N=32768, D=1024, P=4, Fp=256, F=1024.
// ws layout: xd bf16 [N][1024] | Bt bf16 [1024][1024] (f-major, = B^T) | pw f32 [N][4]

typedef float v2f __attribute__((ext_vector_type(2)));
typedef float f32x4 __attribute__((ext_vector_type(4)));
typedef __bf16 bf16x8 __attribute__((ext_vector_type(8)));
typedef unsigned short us4 __attribute__((ext_vector_type(4)));

__device__ __forceinline__ unsigned short f2bf(float f) {
  // round-to-nearest-even f32 -> bf16 (finite inputs only)
  unsigned u = __builtin_bit_cast(unsigned, f);
  u += 0x7fffu + ((u >> 16) & 1u);
  return (unsigned short)(u >> 16);
}

// fp8 e4m3fn roundtrip of two values with independent scales.
// True f32 division to match reference xb/scale rounding exactly.
__device__ __forceinline__ v2f fp8_rt2s(float a, float b, float sa, float sb) {
  int q = __builtin_amdgcn_cvt_pk_fp8_f32(a / sa, b / sb, 0, false);
  v2f r = __builtin_amdgcn_cvt_pk_f32_fp8(q, false);
  r.x *= sa;
  r.y *= sb;
  return r;
}

__device__ __forceinline__ void g2l16(const void* g, void* l) {
  __builtin_amdgcn_global_load_lds(
      (const __attribute__((address_space(1))) unsigned int*)g,
      (__attribute__((address_space(3))) unsigned int*)l,
      16, 0, 0);
}

// ---------------------------------------------------------------------------
// Kernel 1: quantize x (block=128 along D), write bf16 xd, compute info gating
// One wave per row. Lane l, sub-iter j: holds x[row][256j + 4l .. +3].
// 128-elem quant block == one 32-lane half of the wave per j.
// ---------------------------------------------------------------------------
__global__ __launch_bounds__(256) void k_quant_info(
    const float* __restrict__ x, const float* __restrict__ ik,
    const float* __restrict__ ib, unsigned short* __restrict__ xd,
    float* __restrict__ pw, float* __restrict__ cumul, int N) {
  __shared__ f32x4 s_ik[1024];  // dequantized info_kernel rows [d][4]
  const int tid = threadIdx.x;

  // dequant info_kernel (block = min(128,4) = 4, i.e. per-row of 4)
  for (int d = tid; d < 1024; d += 256) {
    f32x4 v = ((const f32x4*)ik)[d];
    float m = fmaxf(fmaxf(fabsf(v.x), fabsf(v.y)), fmaxf(fabsf(v.z), fabsf(v.w)));
    float s = fmaxf(m * (1.0f / 448.0f), 1e-12f);
    v2f lo = fp8_rt2s(v.x, v.y, s, s);
    v2f hi = fp8_rt2s(v.z, v.w, s, s);
    f32x4 dq;
    dq.x = lo.x; dq.y = lo.y; dq.z = hi.x; dq.w = hi.y;
    s_ik[d] = dq;
  }
  __syncthreads();

  const int lane = tid & 63, wv = tid >> 6;
  const int gw = blockIdx.x * 4 + wv;
  const int nw = gridDim.x * 4;
  const f32x4 ibv = *(const f32x4*)ib;

  for (int row = gw; row < N; row += nw) {
    const f32x4* xr = (const f32x4*)(x + (size_t)row * 1024);
    float p0 = 0.f, p1 = 0.f, p2 = 0.f, p3 = 0.f;
#pragma unroll
    for (int j = 0; j < 4; ++j) {
      f32x4 v = xr[j * 64 + lane];
      float m = fmaxf(fmaxf(fabsf(v.x), fabsf(v.y)), fmaxf(fabsf(v.z), fabsf(v.w)));
#pragma unroll
      for (int off = 1; off <= 16; off <<= 1)
        m = fmaxf(m, __shfl_xor(m, off, 64));  // stays within 32-lane half
      float s = fmaxf(m * (1.0f / 448.0f), 1e-12f);
      v2f lo = fp8_rt2s(v.x, v.y, s, s);
      v2f hi = fp8_rt2s(v.z, v.w, s, s);
      const int e = j * 256 + lane * 4;
      us4 h;
      h.x = f2bf(lo.x); h.y = f2bf(lo.y); h.z = f2bf(hi.x); h.w = f2bf(hi.y);
      *(us4*)(xd + (size_t)row * 1024 + e) = h;
      f32x4 k0 = s_ik[e], k1 = s_ik[e + 1], k2 = s_ik[e + 2], k3 = s_ik[e + 3];
      p0 += lo.x * k0.x + lo.y * k1.x + hi.x * k2.x + hi.y * k3.x;
      p1 += lo.x * k0.y + lo.y * k1.y + hi.x * k2.y + hi.y * k3.y;
      p2 += lo.x * k0.z + lo.y * k1.z + hi.x * k2.z + hi.y * k3.z;
      p3 += lo.x * k0.w + lo.y * k1.w + hi.x * k2.w + hi.y * k3.w;
    }
#pragma unroll
    for (int off = 1; off <= 32; off <<= 1) {
      p0 += __shfl_xor(p0, off, 64);
      p1 += __shfl_xor(p1, off, 64);
      p2 += __shfl_xor(p2, off, 64);
      p3 += __shfl_xor(p3, off, 64);
    }
    if (lane == 0) {
      float g0 = 1.f / (1.f + expf(-(p0 + ibv.x)));
      float g1 = 1.f / (1.f + expf(-(p1 + ibv.y)));
      float g2 = 1.f / (1.f + expf(-(p2 + ibv.z)));
      float g3 = 1.f / (1.f + expf(-(p3 + ibv.w)));
      f32x4 cg; cg.x = g0; cg.y = g1; cg.z = g2; cg.w = g3;
      *(f32x4*)(cumul + (size_t)row * 4) = cg;
      f32x4 w;
      w.x = 1.f / (1.f + expf(-((g0 - 0.1f) * 10.f)));
      w.y = 1.f / (1.f + expf(-((g1 - 0.1f) * 10.f)));
      w.z = 1.f / (1.f + expf(-((g2 - 0.1f) * 10.f)));
      w.w = 1.f / (1.f + expf(-((g3 - 0.1f) * 10.f)));
      *(f32x4*)(pw + (size_t)row * 4) = w;
    }
  }
}

// ---------------------------------------------------------------------------
// Kernel 2: roundtrip path_kernels [4][1024][256] (quant block=128 along f),
// write transposed Bt[f_global][d] bf16, f_global = p*256 + f.
// Block handles (p, 32 d-rows). grid = 4*32 = 128 blocks.
// ---------------------------------------------------------------------------
__global__ __launch_bounds__(256) void k_quant_pk(
    const float* __restrict__ pk, unsigned short* __restrict__ bt) {
  __shared__ float s_x[32 * 256];
  __shared__ float s_s[32 * 2];
  const int tid = threadIdx.x;
  const int p = blockIdx.x >> 5;
  const int d0 = (blockIdx.x & 31) * 32;

  const f32x4* src = (const f32x4*)(pk + ((size_t)p * 1024 + d0) * 256);
  f32x4* dst = (f32x4*)s_x;
#pragma unroll
  for (int i = 0; i < 8; ++i) dst[tid + i * 256] = src[tid + i * 256];
  __syncthreads();

  {
    const int d = tid >> 3, seg = tid & 7;  // seg covers f [seg*32, seg*32+32)
    const float* rp = &s_x[d * 256 + seg * 32];
    float m = 0.f;
#pragma unroll
    for (int i = 0; i < 32; ++i) m = fmaxf(m, fabsf(rp[i]));
    m = fmaxf(m, __shfl_xor(m, 1, 64));
    m = fmaxf(m, __shfl_xor(m, 2, 64));  // max over seg quad = 128-f-block
    if ((seg & 3) == 0) s_s[d * 2 + (seg >> 2)] = fmaxf(m * (1.0f / 448.0f), 1e-12f);
  }
  __syncthreads();

  const int f = tid;  // 0..255
  uint4 hv[4];
  unsigned* hw = (unsigned*)hv;
#pragma unroll
  for (int d = 0; d < 32; d += 2) {
    float v0 = s_x[d * 256 + f];
    float sa = s_s[d * 2 + (f >> 7)];
    float v1 = s_x[(d + 1) * 256 + f];
    float sb = s_s[(d + 1) * 2 + (f >> 7)];
    v2f r = fp8_rt2s(v0, v1, sa, sb);
    hw[d >> 1] = (unsigned)f2bf(r.x) | ((unsigned)f2bf(r.y) << 16);
  }
  unsigned short* orow = bt + (size_t)(p * 256 + f) * 1024 + d0;
  uint4* ov = (uint4*)orow;
#pragma unroll
  for (int i = 0; i < 4; ++i) ov[i] = hv[i];
}

// ---------------------------------------------------------------------------
// Kernel 3: C[n][f] = sum_d xd[n][d]*Bt[f][d]; out = (C + pb[f]) * pw[n][f>>8]
// m97 structure: 128x128 tile, BK=64, 4 waves (2x2 of 64x64), 16x16x32 MFMA,
// global_load_lds width-16 staging, two barriers per K-step.
// ---------------------------------------------------------------------------
__global__ __launch_bounds__(256) void k_gemm(
    const unsigned short* __restrict__ xd, const unsigned short* __restrict__ bt,
    const float* __restrict__ pb, const float* __restrict__ pw,
    float* __restrict__ out, int N) {
  __shared__ __align__(16) unsigned short As[128 * 64];
  __shared__ __align__(16) unsigned short Bs[128 * 64];
  const int tid = threadIdx.x;
  const int lane = tid & 63, wv = tid >> 6;
  const int bx = blockIdx.x;
  const int tm = bx >> 3, tn = bx & 7;
  const int m0 = tm * 128, f0 = tn * 128;
  const int wr = wv >> 1, wc = wv & 1;

  f32x4 acc[4][4] = {};
  const int frow = lane & 15;
  const int fk = (lane >> 4) * 8;

  for (int k0 = 0; k0 < 1024; k0 += 64) {
    __syncthreads();
#pragma unroll
    for (int i = 0; i < 4; ++i) {
      const int cbase = (wv * 4 + i) * 64;       // wave-uniform chunk base
      const int chunk = cbase + lane;            // 0..1023, 16B each
      const int r = chunk >> 3, c8 = chunk & 7;
      g2l16(xd + (size_t)(m0 + r) * 1024 + k0 + c8 * 8, (char*)As + cbase * 16);
      g2l16(bt + (size_t)(f0 + r) * 1024 + k0 + c8 * 8, (char*)Bs + cbase * 16);
    }
    __syncthreads();
#pragma unroll
    for (int kk = 0; kk < 64; kk += 32) {
      bf16x8 af[4], bfr[4];
#pragma unroll
      for (int mi = 0; mi < 4; ++mi)
        af[mi] = *(const bf16x8*)&As[(wr * 64 + mi * 16 + frow) * 64 + kk + fk];
#pragma unroll
      for (int ni = 0; ni < 4; ++ni)
        bfr[ni] = *(const bf16x8*)&Bs[(wc * 64 + ni * 16 + frow) * 64 + kk + fk];
#pragma unroll
      for (int mi = 0; mi < 4; ++mi)
#pragma unroll
        for (int ni = 0; ni < 4; ++ni)
          acc[mi][ni] = __builtin_amdgcn_mfma_f32_16x16x32_bf16(
              af[mi], bfr[ni], acc[mi][ni], 0, 0, 0);
    }
  }

  // epilogue: C/D layout col = lane&15, row = (lane>>4)*4 + reg (m89-verified)
  const int r0 = m0 + wr * 64 + (lane >> 4) * 4;
  const int c0 = f0 + wc * 64 + frow;
#pragma unroll
  for (int ni = 0; ni < 4; ++ni) {
    const int c = c0 + ni * 16;
    const float bias = pb[c];
    const int p = c >> 8;
#pragma unroll
    for (int mi = 0; mi < 4; ++mi) {
#pragma unroll
      for (int r = 0; r < 4; ++r) {
        const int row = r0 + mi * 16 + r;
        out[(size_t)row * 1024 + c] = (acc[mi][ni][r] + bias) * pw[row * 4 + p];
      }
    }
  }
}

extern "C" void kernel_launch(void* const* d_in, const int* in_sizes, int n_in,
                              void* d_out, int out_size, void* d_ws, size_t ws_size,
                              hipStream_t stream) {
  const float* x  = (const float*)d_in[0];
  const float* ik = (const float*)d_in[1];
  const float* ib = (const float*)d_in[2];
  const float* pk = (const float*)d_in[3];
  const float* pb = (const float*)d_in[4];
  const int N = in_sizes[0] / 1024;

  float* out = (float*)d_out;
  float* cumul = out + (size_t)N * 1024;

  char* ws = (char*)d_ws;
  unsigned short* xd = (unsigned short*)ws;                                  // N*1024 bf16
  unsigned short* bt = (unsigned short*)(ws + (size_t)N * 1024 * 2);         // 1024*1024 bf16
  float* pw = (float*)(ws + (size_t)N * 1024 * 2 + (size_t)1024 * 1024 * 2); // N*4 f32

  hipLaunchKernelGGL(k_quant_info, dim3(2048), dim3(256), 0, stream,
                     x, ik, ib, xd, pw, cumul, N);
  hipLaunchKernelGGL(k_quant_pk, dim3(128), dim3(256), 0, stream, pk, bt);
  hipLaunchKernelGGL(k_gemm, dim3((N / 128) * 8), dim3(256), 0, stream,
                     xd, bt, pb, pw, out, N);
}